// Round 1
// baseline (549.410 us; speedup 1.0000x reference)
//
#include <hip/hip_runtime.h>
#include <cstdint>
#include <cstddef>

#define NNODES 10000
#define DIM 256
#define MNB 32

// ---------------------------------------------------------------------------
// Kernel 1: attention context. One block (256 thr) per node.
// score[m] = dot(agg[n], agg[nb[m]]) / 16  (masked -> -6.25e8 = -1e10/16)
// ctx[n]   = sum_m softmax(score)[m] * agg[nb[m]]
// ---------------------------------------------------------------------------
__global__ __launch_bounds__(256) void attn_ctx_kernel(
    const float* __restrict__ agg,
    const int* __restrict__ nb_id,
    float* __restrict__ ctx)
{
    const int n = blockIdx.x;
    const int t = threadIdx.x;
    __shared__ float s_agg[DIM];
    __shared__ float s_score[MNB];
    __shared__ int   s_idx[MNB];

    s_agg[t] = agg[(size_t)n * DIM + t];
    if (t < MNB) s_idx[t] = nb_id[n * MNB + t];
    __syncthreads();

    const int wave = t >> 6;
    const int lane = t & 63;

    // each wave computes 8 of the 32 scores
    #pragma unroll
    for (int mi = 0; mi < 8; ++mi) {
        const int m = wave * 8 + mi;
        const int idx = s_idx[m];
        float p = 0.f;
        if (idx >= 0) {
            const float* row = agg + (size_t)idx * DIM;
            #pragma unroll
            for (int j = 0; j < 4; ++j) {
                const int e = lane + 64 * j;
                p = fmaf(s_agg[e], row[e], p);
            }
        }
        #pragma unroll
        for (int off = 32; off; off >>= 1) p += __shfl_down(p, off);
        if (lane == 0) s_score[m] = (idx >= 0) ? p * (1.f / 16.f) : -6.25e8f;
    }
    __syncthreads();

    // redundant softmax in every thread (32 elements, LDS broadcast reads)
    float mx = -INFINITY;
    #pragma unroll
    for (int m = 0; m < MNB; ++m) mx = fmaxf(mx, s_score[m]);
    float w[MNB];
    float denom = 0.f;
    #pragma unroll
    for (int m = 0; m < MNB; ++m) { w[m] = __expf(s_score[m] - mx); denom += w[m]; }
    const float inv = 1.f / denom;

    float c = 0.f;
    #pragma unroll
    for (int m = 0; m < MNB; ++m) {
        const int idx = s_idx[m];
        if (idx >= 0) c = fmaf(w[m] * inv, agg[(size_t)idx * DIM + t], c);
    }
    ctx[(size_t)n * DIM + t] = c;
}

// ---------------------------------------------------------------------------
// Kernel 2: decode_attribute = sigmoid([node|ctx] @ W + b)
// M=10000, N=256, K=512. 64x64 tile / block, 256 thr, 4x4 per thread.
// ---------------------------------------------------------------------------
__global__ __launch_bounds__(256) void attr_kernel(
    const float* __restrict__ node,
    const float* __restrict__ ctx,
    const float* __restrict__ W,
    const float* __restrict__ bias,
    float* __restrict__ out)
{
    const int bi = blockIdx.x;      // 157 row tiles
    const int bj = blockIdx.y;      // 4 col tiles (256/64)
    const int t = threadIdx.x;
    const int tx = t & 15, ty = t >> 4;

    __shared__ float s_a[16][64];   // k-major: s_a[kk][i]
    __shared__ float s_b[16][64];   // k-major: s_b[kk][j]

    float acc[4][4] = {};

    const int row_l = t >> 2;       // 0..63: tile row this thread loads for A
    const int quad  = t & 3;        // which float4 of the 16-wide k slice
    const int gi = bi * 64 + row_l;
    const int brow  = t >> 4;       // 0..15: B k-row
    const int bcol4 = (t & 15) * 4; // B col (float4 granularity)

    for (int kc = 0; kc < 32; ++kc) {   // 32 chunks of 16 over K=512
        const float* Abase = (kc < 16) ? node : ctx;
        const int koff = (kc & 15) * 16;
        float4 av = make_float4(0.f, 0.f, 0.f, 0.f);
        if (gi < NNODES)
            av = *(const float4*)&Abase[(size_t)gi * DIM + koff + quad * 4];
        float4 bv = *(const float4*)&W[(size_t)(kc * 16 + brow) * DIM + bj * 64 + bcol4];

        __syncthreads();
        s_a[quad * 4 + 0][row_l] = av.x;
        s_a[quad * 4 + 1][row_l] = av.y;
        s_a[quad * 4 + 2][row_l] = av.z;
        s_a[quad * 4 + 3][row_l] = av.w;
        *(float4*)&s_b[brow][bcol4] = bv;
        __syncthreads();

        #pragma unroll
        for (int kk = 0; kk < 16; ++kk) {
            float4 a4 = *(const float4*)&s_a[kk][ty * 4];
            float4 b4 = *(const float4*)&s_b[kk][tx * 4];
            float a[4] = {a4.x, a4.y, a4.z, a4.w};
            float b[4] = {b4.x, b4.y, b4.z, b4.w};
            #pragma unroll
            for (int u = 0; u < 4; ++u)
                #pragma unroll
                for (int v = 0; v < 4; ++v)
                    acc[u][v] = fmaf(a[u], b[v], acc[u][v]);
        }
    }

    const int r0 = bi * 64 + ty * 4;
    const int c0 = bj * 64 + tx * 4;
    float4 bb = *(const float4*)&bias[c0];
    float bvals[4] = {bb.x, bb.y, bb.z, bb.w};
    #pragma unroll
    for (int u = 0; u < 4; ++u) {
        if (r0 + u < NNODES) {
            float4 val;
            val.x = 1.f / (1.f + __expf(-(acc[u][0] + bvals[0])));
            val.y = 1.f / (1.f + __expf(-(acc[u][1] + bvals[1])));
            val.z = 1.f / (1.f + __expf(-(acc[u][2] + bvals[2])));
            val.w = 1.f / (1.f + __expf(-(acc[u][3] + bvals[3])));
            *(float4*)&out[(size_t)(r0 + u) * DIM + c0] = val;
        }
    }
}

// ---------------------------------------------------------------------------
// Kernel 3: decode_adj = sigmoid(agg @ agg^T). Symmetric: compute bi<=bj tiles
// only, write tile and its transpose. 64x64 tile / block, 4x4 per thread.
// ---------------------------------------------------------------------------
__global__ __launch_bounds__(256) void adj_kernel(
    const float* __restrict__ agg,
    float* __restrict__ out)
{
    const int bj = blockIdx.x;
    const int bi = blockIdx.y;
    if (bi > bj) return;            // lower triangle handled by mirror write
    const int t = threadIdx.x;
    const int tx = t & 15, ty = t >> 4;

    __shared__ float s_a[16][64];
    __shared__ float s_b[16][64];

    float acc[4][4] = {};

    const int row_l = t >> 2;
    const int quad  = t & 3;
    const int gi = bi * 64 + row_l;
    const int gj = bj * 64 + row_l;

    for (int kc = 0; kc < DIM; kc += 16) {
        float4 av = make_float4(0.f, 0.f, 0.f, 0.f);
        float4 bv = make_float4(0.f, 0.f, 0.f, 0.f);
        if (gi < NNODES) av = *(const float4*)&agg[(size_t)gi * DIM + kc + quad * 4];
        if (gj < NNODES) bv = *(const float4*)&agg[(size_t)gj * DIM + kc + quad * 4];

        __syncthreads();
        s_a[quad * 4 + 0][row_l] = av.x;
        s_a[quad * 4 + 1][row_l] = av.y;
        s_a[quad * 4 + 2][row_l] = av.z;
        s_a[quad * 4 + 3][row_l] = av.w;
        s_b[quad * 4 + 0][row_l] = bv.x;
        s_b[quad * 4 + 1][row_l] = bv.y;
        s_b[quad * 4 + 2][row_l] = bv.z;
        s_b[quad * 4 + 3][row_l] = bv.w;
        __syncthreads();

        #pragma unroll
        for (int kk = 0; kk < 16; ++kk) {
            float4 a4 = *(const float4*)&s_a[kk][ty * 4];
            float4 b4 = *(const float4*)&s_b[kk][tx * 4];
            float a[4] = {a4.x, a4.y, a4.z, a4.w};
            float b[4] = {b4.x, b4.y, b4.z, b4.w};
            #pragma unroll
            for (int u = 0; u < 4; ++u)
                #pragma unroll
                for (int v = 0; v < 4; ++v)
                    acc[u][v] = fmaf(a[u], b[v], acc[u][v]);
        }
    }

    const int r0 = bi * 64 + ty * 4;
    const int c0 = bj * 64 + tx * 4;
    float sg[4][4];
    #pragma unroll
    for (int u = 0; u < 4; ++u)
        #pragma unroll
        for (int v = 0; v < 4; ++v)
            sg[u][v] = 1.f / (1.f + __expf(-acc[u][v]));

    const size_t NN = NNODES;
    if (bi < 156 && bj < 156) {
        #pragma unroll
        for (int u = 0; u < 4; ++u) {
            float4 val = make_float4(sg[u][0], sg[u][1], sg[u][2], sg[u][3]);
            *(float4*)&out[(size_t)(r0 + u) * NN + c0] = val;
        }
        if (bi != bj) {
            #pragma unroll
            for (int v = 0; v < 4; ++v) {
                float4 val = make_float4(sg[0][v], sg[1][v], sg[2][v], sg[3][v]);
                *(float4*)&out[(size_t)(c0 + v) * NN + r0] = val;
            }
        }
    } else {
        #pragma unroll
        for (int u = 0; u < 4; ++u)
            #pragma unroll
            for (int v = 0; v < 4; ++v)
                if (r0 + u < NNODES && c0 + v < NNODES)
                    out[(size_t)(r0 + u) * NN + c0 + v] = sg[u][v];
        if (bi != bj) {
            #pragma unroll
            for (int u = 0; u < 4; ++u)
                #pragma unroll
                for (int v = 0; v < 4; ++v)
                    if (r0 + u < NNODES && c0 + v < NNODES)
                        out[(size_t)(c0 + v) * NN + r0 + u] = sg[u][v];
        }
    }
}

extern "C" void kernel_launch(void* const* d_in, const int* in_sizes, int n_in,
                              void* d_out, int out_size, void* d_ws, size_t ws_size,
                              hipStream_t stream) {
    const float* node = (const float*)d_in[0];   // [N,256]
    const float* agg  = (const float*)d_in[1];   // [N,256]
    const int*   nb   = (const int*)d_in[2];     // [N,32]
    const float* W    = (const float*)d_in[3];   // [512,256]
    const float* bias = (const float*)d_in[4];   // [256]

    float* out_attr = (float*)d_out;                              // N*256
    float* out_adj  = (float*)d_out + (size_t)NNODES * DIM;       // N*N
    float* ctx      = (float*)d_ws;                               // N*256 scratch

    attn_ctx_kernel<<<NNODES, 256, 0, stream>>>(agg, nb, ctx);

    dim3 g2(157, 4);
    attr_kernel<<<g2, 256, 0, stream>>>(node, ctx, W, bias, out_attr);

    dim3 g3(157, 157);
    adj_kernel<<<g3, 256, 0, stream>>>(agg, out_adj);
}